// Round 7
// baseline (333.798 us; speedup 1.0000x reference)
//
#include <hip/hip_runtime.h>
#include <hip/hip_bf16.h>

#define LSEQ   2048
#define DK     64
#define NH     16
#define BS     2
#define DMODEL 1024
#define BH     (BS*NH)    // 32
#define MTOT   (BS*LSEQ)  // 4096

typedef __attribute__((ext_vector_type(8))) short bf16x8;
typedef __attribute__((ext_vector_type(4))) float f32x4;
typedef __attribute__((ext_vector_type(16))) float f32x16;

#define MFMA16(a,b,c) __builtin_amdgcn_mfma_f32_16x16x32_bf16((a),(b),(c),0,0,0)
#define MFMA32(a,b,c) __builtin_amdgcn_mfma_f32_32x32x16_bf16((a),(b),(c),0,0,0)
#define GLD_LDS(g,l) __builtin_amdgcn_global_load_lds((const __attribute__((address_space(1))) void*)(g), (__attribute__((address_space(3))) void*)(l), 16, 0, 0)

__device__ __forceinline__ short f2bs(float f) {
  union { __hip_bfloat16 h; short s; } u; u.h = __float2bfloat16(f); return u.s;
}
__device__ __forceinline__ float b2f(unsigned short s) {
  union { unsigned u; float f; } v; v.u = ((unsigned)s) << 16; return v.f;
}
// cheap round-half-up bf16 (inputs guaranteed finite)
__device__ __forceinline__ unsigned short f2bs_c(float f) {
  union { float f; unsigned u; } v; v.f = f;
  return (unsigned short)((v.u + 0x8000u) >> 16);
}
__device__ __forceinline__ unsigned pk2c(float lo, float hi) {
  union { float f; unsigned u; } a, b; a.f = lo; b.f = hi;
  return ((a.u + 0x8000u) >> 16) | ((b.u + 0x8000u) & 0xffff0000u);
}
__device__ __forceinline__ unsigned pk2(float lo, float hi) {
  return (unsigned)(unsigned short)f2bs(lo) | (((unsigned)(unsigned short)f2bs(hi)) << 16);
}

// ---------------- f32 -> bf16 flat convert (vectorized) ----------------
__global__ __launch_bounds__(256) void cvt_bf16_k(const float* __restrict__ in,
                                                  short* __restrict__ out, int n8) {
  for (int i = blockIdx.x * blockDim.x + threadIdx.x; i < n8; i += gridDim.x * blockDim.x) {
    const float4* p = (const float4*)in + (size_t)i * 2;
    float4 a = p[0], b = p[1];
    uint4 o;
    o.x = pk2(a.x, a.y); o.y = pk2(a.z, a.w);
    o.z = pk2(b.x, b.y); o.w = pk2(b.z, b.w);
    ((uint4*)out)[i] = o;
  }
}

// ---------------- f32 [K][N] -> bf16 transposed [N][K] ----------------
__global__ __launch_bounds__(256) void cvt_tr_k(const float* __restrict__ W,
                                                short* __restrict__ Wt,
                                                int Krows, int Ncols) {
  __shared__ float tile[32][33];
  int n0 = blockIdx.x * 32, k0 = blockIdx.y * 32;
  int t = threadIdx.x;
#pragma unroll
  for (int i = 0; i < 4; ++i) {
    int idx = t + i * 256; int r = idx >> 5, c = idx & 31;
    tile[r][c] = W[(size_t)(k0 + r) * Ncols + n0 + c];
  }
  __syncthreads();
#pragma unroll
  for (int i = 0; i < 4; ++i) {
    int idx = t + i * 256; int r = idx >> 5, c = idx & 31;
    Wt[(size_t)(n0 + r) * Krows + k0 + c] = f2bs(tile[c][r]);
  }
}

// ---------------- 128x128-tile bf16 GEMM, K=1024 ----------------
__global__ __launch_bounds__(256) void gemm128_k(
    const short* __restrict__ A, const short* __restrict__ Bt,
    const float* __restrict__ bias, int mode,
    float* __restrict__ outF,
    short* __restrict__ Qb, short* __restrict__ Kb, short* __restrict__ VTb) {
  __shared__ short As[128 * 64];
  __shared__ short Bs[128 * 64];
  int tid = threadIdx.x, w = tid >> 6, ln = tid & 63, lg = ln >> 4, lr = ln & 15;
  int m0 = blockIdx.x * 128, n0 = blockIdx.y * 128;
  int wr = w >> 1, wc = w & 1;
  f32x4 acc[4][4] = {};

  for (int k0 = 0; k0 < 1024; k0 += 64) {
    __syncthreads();
#pragma unroll
    for (int i = 0; i < 4; ++i) {
      int cb = w * 64 + i * 256;
      int c = cb + ln;
      GLD_LDS(A  + (size_t)(m0 + (c >> 3)) * 1024 + k0 + (c & 7) * 8, &As[cb * 8]);
      GLD_LDS(Bt + (size_t)(n0 + (c >> 3)) * 1024 + k0 + (c & 7) * 8, &Bs[cb * 8]);
    }
    __syncthreads();
#pragma unroll
    for (int kh = 0; kh < 2; ++kh) {
      bf16x8 af[4], bfr[4];
#pragma unroll
      for (int mi = 0; mi < 4; ++mi)
        af[mi] = *(const bf16x8*)&As[(wr * 64 + mi * 16 + lr) * 64 + kh * 32 + lg * 8];
#pragma unroll
      for (int ni = 0; ni < 4; ++ni)
        bfr[ni] = *(const bf16x8*)&Bs[(wc * 64 + ni * 16 + lr) * 64 + kh * 32 + lg * 8];
#pragma unroll
      for (int mi = 0; mi < 4; ++mi)
#pragma unroll
        for (int ni = 0; ni < 4; ++ni)
          acc[mi][ni] = MFMA16(af[mi], bfr[ni], acc[mi][ni]);
    }
  }

#pragma unroll
  for (int ni = 0; ni < 4; ++ni) {
    int n = n0 + wc * 64 + ni * 16 + lr;
    float bv = bias[n];
    int part = n >> 10, cc = n & 1023, h = cc >> 6, dd = cc & 63;
#pragma unroll
    for (int mi = 0; mi < 4; ++mi) {
      int mbase = m0 + wr * 64 + mi * 16 + 4 * lg;
      float vv[4];
#pragma unroll
      for (int r = 0; r < 4; ++r) vv[r] = acc[mi][ni][r] + bv;
      if (mode == 1) {
#pragma unroll
        for (int r = 0; r < 4; ++r) outF[(size_t)(mbase + r) * 1024 + n] = vv[r];
      } else if (part == 2) {
        int b = mbase >> 11, tok = mbase & 2047, bh = b * NH + h;
        uint2 pk; pk.x = pk2c(vv[0], vv[1]); pk.y = pk2c(vv[2], vv[3]);
        *(uint2*)&VTb[((size_t)bh * DK + dd) * LSEQ + tok] = pk;
      } else {
        short* dst = (part == 0) ? Qb : Kb;
#pragma unroll
        for (int r = 0; r < 4; ++r) {
          int m = mbase + r;
          int b = m >> 11, tok = m & 2047, bh = b * NH + h;
          dst[((size_t)bh * LSEQ + tok) * DK + dd] = (short)f2bs_c(vv[r]);
        }
      }
    }
  }
}

// ---------------- per-row squared norms ----------------
__global__ __launch_bounds__(256) void norms_k(
    const short* __restrict__ Qm, const short* __restrict__ Qs,
    const short* __restrict__ Km, const short* __restrict__ Ks,
    float* __restrict__ sqq, float* __restrict__ sqk) {
  int id = blockIdx.x * 256 + threadIdx.x;  // 0..131071
  int row = id & 65535;
  const short* p1 = (id < 65536) ? Qm : Km;
  const short* p2 = (id < 65536) ? Qs : Ks;
  float* outp = (id < 65536) ? sqq : sqk;
  const uint4* a = (const uint4*)(p1 + (size_t)row * DK);
  const uint4* b = (const uint4*)(p2 + (size_t)row * DK);
  float s = 0.f;
#pragma unroll
  for (int i = 0; i < 8; ++i) {
    uint4 x = a[i], y = b[i];
    unsigned vx[4] = {x.x, x.y, x.z, x.w};
    unsigned vy[4] = {y.x, y.y, y.z, y.w};
#pragma unroll
    for (int j = 0; j < 4; ++j) {
      float l1 = b2f((unsigned short)(vx[j] & 0xffff)), h1 = b2f((unsigned short)(vx[j] >> 16));
      float l2 = b2f((unsigned short)(vy[j] & 0xffff)), h2 = b2f((unsigned short)(vy[j] >> 16));
      s += l1 * l1 + h1 * h1 + l2 * l2 + h2 * h2;
    }
  }
  outp[row] = s;
}

// ---------------- fused Wasserstein attention (32x32 MFMA) ----------------
// grid (L/64, BH); 256 threads = 4 waves = (qg = w&1) x (ks = w>>1).
// Wave: 32 q-rows [q0+32*qg, +32), k-half [ks*32, +32) of each 64-k tile.
// QK^T swapped (S[k][q]) with 32x32x16 MFMA: one A-frag LDS read feeds
// 2x the FLOP of the old 16x16x32 path. P->PV B-frags built in-register
// via pk2c + v_permlane32_swap_b32 (no P LDS traffic). K/V staged by
// global_load_lds with pre-swizzled source cols; reads XOR-swizzled
// (byte ^= (row&7)<<4) -> conflict-free (T2, rule #21).
__global__ __launch_bounds__(256, 3) void attn_k(
    const short* __restrict__ Qm, const short* __restrict__ Km, const short* __restrict__ VmT,
    const short* __restrict__ Qs, const short* __restrict__ Ks, const short* __restrict__ VsT,
    const float* __restrict__ sqq, const float* __restrict__ sqk,
    short* __restrict__ Om, short* __restrict__ Os) {
  int bh = blockIdx.y;
  int q0 = blockIdx.x * 64;
  int tid = threadIdx.x, w = tid >> 6, ln = tid & 63;
  int l31 = ln & 31, h = ln >> 5;
  int qg = w & 1, ks = w >> 1;

  // pool layout: [0,8K) Km [64][64]swz | [8K,16K) Ks | [16K,32K) Vt [128][64]swz
  // epilogue reuse: [0,32K) O-scratch, [32K, +512) prs-scratch
  __shared__ __align__(16) char pool[33280];
  short* poolS = (short*)pool;

  const size_t bhQ = (size_t)bh * LSEQ * DK;

  // Q fragments (B operand: col = q = l31, k-dim = d = dblk*16 + h*8 + j)
  int q = q0 + qg * 32 + l31;
  bf16x8 qmf[4], qsf[4];
#pragma unroll
  for (int d = 0; d < 4; ++d) {
    qmf[d] = *(const bf16x8*)(Qm + bhQ + (size_t)q * DK + d * 16 + h * 8);
    qsf[d] = *(const bf16x8*)(Qs + bhQ + (size_t)q * DK + d * 16 + h * 8);
  }
  float sqQ = sqq[(size_t)bh * LSEQ + q];
  const float* sqkp = sqk + (size_t)bh * LSEQ;

  // staging: 32 wave-loads of 1KB per tile; wave w does j = w*8 + i.
  // LDS linear (slot j*64+ln, 16B each); global source col pre-swizzled:
  // cswz = (ln&7) ^ (row&7)  (involution with the read-side XOR).
  const short* sb[8];
  int st[8];
#pragma unroll
  for (int i = 0; i < 8; ++i) {
    int j = w * 8 + i;
    int rr = j * 8 + (ln >> 3);
    int cs = ((ln & 7) ^ (rr & 7)) * 8;
    if (j < 8)       { sb[i] = Km + bhQ + (size_t)rr * DK + cs;                  st[i] = 64 * DK; }
    else if (j < 16) { sb[i] = Ks + bhQ + (size_t)(rr - 64) * DK + cs;           st[i] = 64 * DK; }
    else if (j < 24) { sb[i] = VmT + ((size_t)bh * DK + (rr - 128)) * LSEQ + cs; st[i] = 64; }
    else             { sb[i] = VsT + ((size_t)bh * DK + (rr - 192)) * LSEQ + cs; st[i] = 64; }
  }

  f32x16 acc[4] = {};
  float prs = 0.f;

  const int krow = ks * 32 + l31;
  const int kswz = (krow & 7) << 4;

  const int NT = LSEQ / 64;
  for (int t = 0; t < NT; ++t) {
    __syncthreads();   // all reads of previous tile done
#pragma unroll
    for (int i = 0; i < 8; ++i) {
      int j = w * 8 + i;
      GLD_LDS(sb[i] + (size_t)t * st[i], poolS + j * 512);
    }
    __syncthreads();   // vmcnt(0) drained before barrier -> tile visible

    // QK^T: S[k][q] for this wave's 32-k half, 32 q
    f32x16 sm = {}, ss = {};
#pragma unroll
    for (int d = 0; d < 4; ++d) {
      bf16x8 am = *(const bf16x8*)((char*)poolS + krow * 128 + ((d * 32 + h * 16) ^ kswz));
      bf16x8 as = *(const bf16x8*)((char*)poolS + 8192 + krow * 128 + ((d * 32 + h * 16) ^ kswz));
      sm = MFMA32(am, qmf[d], sm);
      ss = MFMA32(as, qsf[d], ss);
    }

    // softmax numerator; S row k = (reg&3) + 8*(reg>>2) + 4*h (k-local)
    float pv[16];
    int k0b = t * 64 + ks * 32;
#pragma unroll
    for (int rq = 0; rq < 4; ++rq) {
      f32x4 rsk = *(const f32x4*)&sqkp[k0b + 8 * rq + 4 * h];
#pragma unroll
      for (int r = 0; r < 4; ++r) {
        int i = rq * 4 + r;
        float w2 = fmaf(-2.f, sm[i] + ss[i], sqQ + rsk[r]);
        float wd = __builtin_amdgcn_sqrtf(fmaxf(w2, 0.f));
        float sim = __expf(-wd);
        float p = __expf(sim);
        prs += p;
        pv[i] = p;
      }
    }
    // pack to bf16 + lane-half swap -> PV B-frags (k = ks*32 + kblk*16)
    unsigned u0 = pk2c(pv[0], pv[1]),   u1 = pk2c(pv[2], pv[3]);
    unsigned u2 = pk2c(pv[4], pv[5]),   u3 = pk2c(pv[6], pv[7]);
    unsigned u4 = pk2c(pv[8], pv[9]),   u5 = pk2c(pv[10], pv[11]);
    unsigned u6 = pk2c(pv[12], pv[13]), u7 = pk2c(pv[14], pv[15]);
    asm volatile("v_permlane32_swap_b32 %0, %1" : "+v"(u0), "+v"(u2));
    asm volatile("v_permlane32_swap_b32 %0, %1" : "+v"(u1), "+v"(u3));
    asm volatile("v_permlane32_swap_b32 %0, %1" : "+v"(u4), "+v"(u6));
    asm volatile("v_permlane32_swap_b32 %0, %1" : "+v"(u5), "+v"(u7));
    union { uint4 u; bf16x8 v; } f0, f1;
    f0.u.x = u0; f0.u.y = u1; f0.u.z = u2; f0.u.w = u3;
    f1.u.x = u4; f1.u.y = u5; f1.u.z = u6; f1.u.w = u7;

    // PV: acc[vblk] += V-frag(32v x 16k) x P-frag
#pragma unroll
    for (int vblk = 0; vblk < 4; ++vblk) {
      int vrow = vblk * 32 + l31;
      int vswz = (vrow & 7) << 4;
      const char* vbase = (const char*)poolS + 16384 + vrow * 128;
      bf16x8 v0 = *(const bf16x8*)(vbase + ((ks * 64 + h * 16) ^ vswz));
      bf16x8 v1 = *(const bf16x8*)(vbase + ((ks * 64 + 32 + h * 16) ^ vswz));
      acc[vblk] = MFMA32(v0, f0.v, acc[vblk]);
      acc[vblk] = MFMA32(v1, f1.v, acc[vblk]);
    }
  }

  // row-sum: reduce over lane halves (k-coverage split by h)
  prs += __shfl_xor(prs, 32);

  // combine k-halves (ks=1 -> ks=0) through LDS scratch
  float* scr  = (float*)pool;
  float* scrP = (float*)(pool + 32768);
  __syncthreads();
  if (ks == 1) {
#pragma unroll
    for (int vblk = 0; vblk < 4; ++vblk)
#pragma unroll
      for (int rq = 0; rq < 4; ++rq) {
        f32x4 qd;
        qd[0] = acc[vblk][rq * 4 + 0]; qd[1] = acc[vblk][rq * 4 + 1];
        qd[2] = acc[vblk][rq * 4 + 2]; qd[3] = acc[vblk][rq * 4 + 3];
        *(f32x4*)&scr[(((qg * 4 + vblk) * 4 + rq) * 64 + ln) * 4] = qd;
      }
    scrP[qg * 64 + ln] = prs;
  }
  __syncthreads();
  if (ks == 0) {
    float inv = 1.f / (prs + scrP[qg * 64 + ln]);
    int b = bh >> 4, hh = bh & 15;
    size_t orow = ((size_t)(b * LSEQ + q)) * DMODEL + hh * DK;
#pragma unroll
    for (int vblk = 0; vblk < 4; ++vblk) {
      short* obuf = (vblk < 2) ? Om : Os;
      int vbase = (vblk & 1) * 32 + 4 * h;
#pragma unroll
      for (int rq = 0; rq < 4; ++rq) {
        f32x4 od = *(const f32x4*)&scr[(((qg * 4 + vblk) * 4 + rq) * 64 + ln) * 4];
        float o0 = (acc[vblk][rq * 4 + 0] + od[0]) * inv;
        float o1 = (acc[vblk][rq * 4 + 1] + od[1]) * inv;
        float o2 = (acc[vblk][rq * 4 + 2] + od[2]) * inv;
        float o3 = (acc[vblk][rq * 4 + 3] + od[3]) * inv;
        uint2 pk; pk.x = pk2c(o0, o1); pk.y = pk2c(o2, o3);
        *(uint2*)(obuf + orow + vbase + 8 * rq) = pk;
      }
    }
  }
}

extern "C" void kernel_launch(void* const* d_in, const int* in_sizes, int n_in,
                              void* d_out, int out_size, void* d_ws, size_t ws_size,
                              hipStream_t stream) {
  const float* mu    = (const float*)d_in[0];
  const float* sigma = (const float*)d_in[1];
  const float* Wqm   = (const float*)d_in[2];
  const float* bqm   = (const float*)d_in[3];
  const float* Wqs   = (const float*)d_in[4];
  const float* bqs   = (const float*)d_in[5];
  const float* Wo    = (const float*)d_in[6];
  const float* bo    = (const float*)d_in[7];
  float* out = (float*)d_out;
  char* ws = (char*)d_ws;
  const size_t MB = 1u << 20;

  short* Amu   = (short*)(ws + 0);        // 8MB, reused as Om
  short* Asg   = (short*)(ws + 8 * MB);   // 8MB, reused as Os (contiguous with Om)
  short* Wqm_t = (short*)(ws + 16 * MB);  // 6MB
  short* Wqs_t = (short*)(ws + 22 * MB);  // 6MB
  short* Wo_t  = (short*)(ws + 28 * MB);  // 2MB
  short* Qm    = (short*)(ws + 30 * MB);  // 8MB each below
  short* Km    = (short*)(ws + 38 * MB);
  short* VmT   = (short*)(ws + 46 * MB);
  short* Qs    = (short*)(ws + 54 * MB);
  short* Ks    = (short*)(ws + 62 * MB);
  short* VsT   = (short*)(ws + 70 * MB);
  float* sqq   = (float*)(ws + 78 * MB);            // 256KB
  float* sqk   = (float*)(ws + 78 * MB + 256 * 1024);
  short* Om = Amu;
  short* Os = Asg;

  cvt_bf16_k<<<2048, 256, 0, stream>>>(mu, Amu, MTOT * DMODEL / 8);
  cvt_bf16_k<<<2048, 256, 0, stream>>>(sigma, Asg, MTOT * DMODEL / 8);
  cvt_tr_k<<<dim3(96, 32), 256, 0, stream>>>(Wqm, Wqm_t, 1024, 3072);
  cvt_tr_k<<<dim3(96, 32), 256, 0, stream>>>(Wqs, Wqs_t, 1024, 3072);
  cvt_tr_k<<<dim3(32, 32), 256, 0, stream>>>(Wo, Wo_t, 1024, 1024);

  gemm128_k<<<dim3(32, 24), 256, 0, stream>>>(Amu, Wqm_t, bqm, 0, nullptr, Qm, Km, VmT);
  gemm128_k<<<dim3(32, 24), 256, 0, stream>>>(Asg, Wqs_t, bqs, 0, nullptr, Qs, Ks, VsT);

  norms_k<<<512, 256, 0, stream>>>(Qm, Qs, Km, Ks, sqq, sqk);

  attn_k<<<dim3(LSEQ / 64, BH), 256, 0, stream>>>(Qm, Km, VmT, Qs, Ks, VsT, sqq, sqk, Om, Os);

  // out-proj for mu and sigma as ONE GEMM (Om|Os contiguous, M=8192)
  gemm128_k<<<dim3(64, 8), 256, 0, stream>>>(Om, Wo_t, bo, 1, out, nullptr, nullptr, nullptr);
}

// Round 8
// 276.155 us; speedup vs baseline: 1.2087x; 1.2087x over previous
//
#include <hip/hip_runtime.h>
#include <hip/hip_bf16.h>

#define LSEQ   2048
#define DK     64
#define NH     16
#define BS     2
#define DMODEL 1024
#define BH     (BS*NH)    // 32
#define MTOT   (BS*LSEQ)  // 4096

typedef __attribute__((ext_vector_type(8))) short bf16x8;
typedef __attribute__((ext_vector_type(4))) float f32x4;
typedef __attribute__((ext_vector_type(16))) float f32x16;

#define MFMA16(a,b,c) __builtin_amdgcn_mfma_f32_16x16x32_bf16((a),(b),(c),0,0,0)
#define MFMA32(a,b,c) __builtin_amdgcn_mfma_f32_32x32x16_bf16((a),(b),(c),0,0,0)
#define GLD_LDS(g,l) __builtin_amdgcn_global_load_lds((const __attribute__((address_space(1))) void*)(g), (__attribute__((address_space(3))) void*)(l), 16, 0, 0)

__device__ __forceinline__ short f2bs(float f) {
  union { __hip_bfloat16 h; short s; } u; u.h = __float2bfloat16(f); return u.s;
}
__device__ __forceinline__ float b2f(unsigned short s) {
  union { unsigned u; float f; } v; v.u = ((unsigned)s) << 16; return v.f;
}
// cheap round-half-up bf16 (inputs guaranteed finite)
__device__ __forceinline__ unsigned short f2bs_c(float f) {
  union { float f; unsigned u; } v; v.f = f;
  return (unsigned short)((v.u + 0x8000u) >> 16);
}
__device__ __forceinline__ unsigned pk2c(float lo, float hi) {
  union { float f; unsigned u; } a, b; a.f = lo; b.f = hi;
  return ((a.u + 0x8000u) >> 16) | ((b.u + 0x8000u) & 0xffff0000u);
}
__device__ __forceinline__ unsigned pk2(float lo, float hi) {
  return (unsigned)(unsigned short)f2bs(lo) | (((unsigned)(unsigned short)f2bs(hi)) << 16);
}

// ---------------- f32 -> bf16 flat convert (vectorized) ----------------
__global__ __launch_bounds__(256) void cvt_bf16_k(const float* __restrict__ in,
                                                  short* __restrict__ out, int n8) {
  for (int i = blockIdx.x * blockDim.x + threadIdx.x; i < n8; i += gridDim.x * blockDim.x) {
    const float4* p = (const float4*)in + (size_t)i * 2;
    float4 a = p[0], b = p[1];
    uint4 o;
    o.x = pk2(a.x, a.y); o.y = pk2(a.z, a.w);
    o.z = pk2(b.x, b.y); o.w = pk2(b.z, b.w);
    ((uint4*)out)[i] = o;
  }
}

// ---------------- f32 [K][N] -> bf16 transposed [N][K] ----------------
__global__ __launch_bounds__(256) void cvt_tr_k(const float* __restrict__ W,
                                                short* __restrict__ Wt,
                                                int Krows, int Ncols) {
  __shared__ float tile[32][33];
  int n0 = blockIdx.x * 32, k0 = blockIdx.y * 32;
  int t = threadIdx.x;
#pragma unroll
  for (int i = 0; i < 4; ++i) {
    int idx = t + i * 256; int r = idx >> 5, c = idx & 31;
    tile[r][c] = W[(size_t)(k0 + r) * Ncols + n0 + c];
  }
  __syncthreads();
#pragma unroll
  for (int i = 0; i < 4; ++i) {
    int idx = t + i * 256; int r = idx >> 5, c = idx & 31;
    Wt[(size_t)(n0 + r) * Krows + k0 + c] = f2bs(tile[c][r]);
  }
}

// ---------------- 128x128-tile bf16 GEMM, K=1024 ----------------
__global__ __launch_bounds__(256) void gemm128_k(
    const short* __restrict__ A, const short* __restrict__ Bt,
    const float* __restrict__ bias, int mode,
    float* __restrict__ outF,
    short* __restrict__ Qb, short* __restrict__ Kb, short* __restrict__ VTb) {
  __shared__ short As[128 * 64];
  __shared__ short Bs[128 * 64];
  int tid = threadIdx.x, w = tid >> 6, ln = tid & 63, lg = ln >> 4, lr = ln & 15;
  int m0 = blockIdx.x * 128, n0 = blockIdx.y * 128;
  int wr = w >> 1, wc = w & 1;
  f32x4 acc[4][4] = {};

  for (int k0 = 0; k0 < 1024; k0 += 64) {
    __syncthreads();
#pragma unroll
    for (int i = 0; i < 4; ++i) {
      int cb = w * 64 + i * 256;
      int c = cb + ln;
      GLD_LDS(A  + (size_t)(m0 + (c >> 3)) * 1024 + k0 + (c & 7) * 8, &As[cb * 8]);
      GLD_LDS(Bt + (size_t)(n0 + (c >> 3)) * 1024 + k0 + (c & 7) * 8, &Bs[cb * 8]);
    }
    __syncthreads();
#pragma unroll
    for (int kh = 0; kh < 2; ++kh) {
      bf16x8 af[4], bfr[4];
#pragma unroll
      for (int mi = 0; mi < 4; ++mi)
        af[mi] = *(const bf16x8*)&As[(wr * 64 + mi * 16 + lr) * 64 + kh * 32 + lg * 8];
#pragma unroll
      for (int ni = 0; ni < 4; ++ni)
        bfr[ni] = *(const bf16x8*)&Bs[(wc * 64 + ni * 16 + lr) * 64 + kh * 32 + lg * 8];
#pragma unroll
      for (int mi = 0; mi < 4; ++mi)
#pragma unroll
        for (int ni = 0; ni < 4; ++ni)
          acc[mi][ni] = MFMA16(af[mi], bfr[ni], acc[mi][ni]);
    }
  }

#pragma unroll
  for (int ni = 0; ni < 4; ++ni) {
    int n = n0 + wc * 64 + ni * 16 + lr;
    float bv = bias[n];
    int part = n >> 10, cc = n & 1023, h = cc >> 6, dd = cc & 63;
#pragma unroll
    for (int mi = 0; mi < 4; ++mi) {
      int mbase = m0 + wr * 64 + mi * 16 + 4 * lg;
      float vv[4];
#pragma unroll
      for (int r = 0; r < 4; ++r) vv[r] = acc[mi][ni][r] + bv;
      if (mode == 1) {
#pragma unroll
        for (int r = 0; r < 4; ++r) outF[(size_t)(mbase + r) * 1024 + n] = vv[r];
      } else if (part == 2) {
        int b = mbase >> 11, tok = mbase & 2047, bh = b * NH + h;
        uint2 pk; pk.x = pk2c(vv[0], vv[1]); pk.y = pk2c(vv[2], vv[3]);
        *(uint2*)&VTb[((size_t)bh * DK + dd) * LSEQ + tok] = pk;
      } else {
        short* dst = (part == 0) ? Qb : Kb;
#pragma unroll
        for (int r = 0; r < 4; ++r) {
          int m = mbase + r;
          int b = m >> 11, tok = m & 2047, bh = b * NH + h;
          dst[((size_t)bh * LSEQ + tok) * DK + dd] = (short)f2bs_c(vv[r]);
        }
      }
    }
  }
}

// ---------------- per-row squared norms ----------------
__global__ __launch_bounds__(256) void norms_k(
    const short* __restrict__ Qm, const short* __restrict__ Qs,
    const short* __restrict__ Km, const short* __restrict__ Ks,
    float* __restrict__ sqq, float* __restrict__ sqk) {
  int id = blockIdx.x * 256 + threadIdx.x;  // 0..131071
  int row = id & 65535;
  const short* p1 = (id < 65536) ? Qm : Km;
  const short* p2 = (id < 65536) ? Qs : Ks;
  float* outp = (id < 65536) ? sqq : sqk;
  const uint4* a = (const uint4*)(p1 + (size_t)row * DK);
  const uint4* b = (const uint4*)(p2 + (size_t)row * DK);
  float s = 0.f;
#pragma unroll
  for (int i = 0; i < 8; ++i) {
    uint4 x = a[i], y = b[i];
    unsigned vx[4] = {x.x, x.y, x.z, x.w};
    unsigned vy[4] = {y.x, y.y, y.z, y.w};
#pragma unroll
    for (int j = 0; j < 4; ++j) {
      float l1 = b2f((unsigned short)(vx[j] & 0xffff)), h1 = b2f((unsigned short)(vx[j] >> 16));
      float l2 = b2f((unsigned short)(vy[j] & 0xffff)), h2 = b2f((unsigned short)(vy[j] >> 16));
      s += l1 * l1 + h1 * h1 + l2 * l2 + h2 * h2;
    }
  }
  outp[row] = s;
}

// ---------------- fused Wasserstein attention (32x32 MFMA, dbuf) ----------------
// grid (L/64, BH); 256 threads = 4 waves = (qg = w&1) x (ks = w>>1).
// m97-style pipeline: double-buffered LDS (2 x 32KB); per tile:
//   barrier (drains vmcnt -> tile t visible) -> issue gld_lds for t+1 into
//   buf^1 -> compute tile t.  Loads fly during compute; one barrier/tile.
// Swizzle: LDS[row][s] = G[row][s ^ swz(row)], swz = (row&7) ^ ((row>>3)&3)
// (pre-swizzled global source; both-sides rule #21). Reads bank-balanced.
// P->PV B-frags in-register via pk2c + v_permlane32_swap_b32.
__global__ __launch_bounds__(256, 2) void attn_k(
    const short* __restrict__ Qm, const short* __restrict__ Km, const short* __restrict__ VmT,
    const short* __restrict__ Qs, const short* __restrict__ Ks, const short* __restrict__ VsT,
    const float* __restrict__ sqq, const float* __restrict__ sqk,
    short* __restrict__ Om, short* __restrict__ Os) {
  int bh = blockIdx.y;
  int q0 = blockIdx.x * 64;
  int tid = threadIdx.x, w = tid >> 6, ln = tid & 63;
  int l31 = ln & 31, h = ln >> 5;
  int qg = w & 1, ks = w >> 1;

  // buf layout (per 32KB half): [0,8K) Km [64 rows][64 sh] | [8K,16K) Ks
  // | [16K,32K) Vt [128 rows][64 sh].  Epilogue reuses [0,33280).
  __shared__ __align__(16) char pool[65536];
  short* poolS = (short*)pool;

  const size_t bhQ = (size_t)bh * LSEQ * DK;

  // Q fragments (B operand: col = q = l31, k-dim d = dblk*16 + h*8 + j)
  int q = q0 + qg * 32 + l31;
  bf16x8 qmf[4], qsf[4];
#pragma unroll
  for (int d = 0; d < 4; ++d) {
    qmf[d] = *(const bf16x8*)(Qm + bhQ + (size_t)q * DK + d * 16 + h * 8);
    qsf[d] = *(const bf16x8*)(Qs + bhQ + (size_t)q * DK + d * 16 + h * 8);
  }
  float sqQ = sqq[(size_t)bh * LSEQ + q];
  const float* sqkp = sqk + (size_t)bh * LSEQ;

  // staging: 32 wave-loads of 1KB per tile; wave w does j = w*8 + i.
  // LDS dest linear (slot j*1024B + lane*16B); global source col
  // pre-swizzled: cs = (ln&7) ^ (rr&7) ^ ((rr>>3)&3).
  const short* sb[8];
  int st[8];
#pragma unroll
  for (int i = 0; i < 8; ++i) {
    int j = w * 8 + i;
    int rr = j * 8 + (ln >> 3);
    int cs = ((ln & 7) ^ (rr & 7) ^ ((rr >> 3) & 3)) * 8;
    if (j < 8)       { sb[i] = Km + bhQ + (size_t)rr * DK + cs;                  st[i] = 64 * DK; }
    else if (j < 16) { sb[i] = Ks + bhQ + (size_t)(rr - 64) * DK + cs;           st[i] = 64 * DK; }
    else if (j < 24) { sb[i] = VmT + ((size_t)bh * DK + (rr - 128)) * LSEQ + cs; st[i] = 64; }
    else             { sb[i] = VsT + ((size_t)bh * DK + (rr - 192)) * LSEQ + cs; st[i] = 64; }
  }

  f32x16 acc[4] = {};
  float prs = 0.f;

  const int krow = ks * 32 + l31;
  const int kswz = ((krow & 7) ^ ((krow >> 3) & 3)) << 4;

  // prolog: issue tile 0 into buf 0
#pragma unroll
  for (int i = 0; i < 8; ++i)
    GLD_LDS(sb[i], poolS + (w * 8 + i) * 512);

  const int NT = LSEQ / 64;
  for (int t = 0; t < NT; ++t) {
    __syncthreads();   // drains vmcnt(0): tile t visible; prev buf reads done
    int cur = (t & 1) * 16384;           // shorts
    // issue loads for tile t+1 into the other buffer (fly during compute)
    if (t + 1 < NT) {
      int nxt = ((t + 1) & 1) * 16384;
#pragma unroll
      for (int i = 0; i < 8; ++i)
        GLD_LDS(sb[i] + (size_t)(t + 1) * st[i], poolS + nxt + (w * 8 + i) * 512);
    }
    const char* base = (const char*)(poolS + cur);

    // QK^T: S[k][q] for this wave's 32-k half, 32 q
    f32x16 sm = {}, ss = {};
#pragma unroll
    for (int d = 0; d < 4; ++d) {
      bf16x8 am = *(const bf16x8*)(base + krow * 128 + ((d * 32 + h * 16) ^ kswz));
      bf16x8 as = *(const bf16x8*)(base + 8192 + krow * 128 + ((d * 32 + h * 16) ^ kswz));
      sm = MFMA32(am, qmf[d], sm);
      ss = MFMA32(as, qsf[d], ss);
    }

    // softmax numerator; S row k_local = (reg&3) + 8*(reg>>2) + 4*h
    float pv[16];
    int k0b = t * 64 + ks * 32;
#pragma unroll
    for (int rq = 0; rq < 4; ++rq) {
      f32x4 rsk = *(const f32x4*)&sqkp[k0b + 8 * rq + 4 * h];
#pragma unroll
      for (int r = 0; r < 4; ++r) {
        int i = rq * 4 + r;
        float w2 = fmaf(-2.f, sm[i] + ss[i], sqQ + rsk[r]);
        float wd = __builtin_amdgcn_sqrtf(fmaxf(w2, 0.f));
        float sim = __expf(-wd);
        float p = __expf(sim);
        prs += p;
        pv[i] = p;
      }
    }
    // pack to bf16 + lane-half swap -> PV B-frags
    unsigned u0 = pk2c(pv[0], pv[1]),   u1 = pk2c(pv[2], pv[3]);
    unsigned u2 = pk2c(pv[4], pv[5]),   u3 = pk2c(pv[6], pv[7]);
    unsigned u4 = pk2c(pv[8], pv[9]),   u5 = pk2c(pv[10], pv[11]);
    unsigned u6 = pk2c(pv[12], pv[13]), u7 = pk2c(pv[14], pv[15]);
    asm volatile("v_permlane32_swap_b32 %0, %1" : "+v"(u0), "+v"(u2));
    asm volatile("v_permlane32_swap_b32 %0, %1" : "+v"(u1), "+v"(u3));
    asm volatile("v_permlane32_swap_b32 %0, %1" : "+v"(u4), "+v"(u6));
    asm volatile("v_permlane32_swap_b32 %0, %1" : "+v"(u5), "+v"(u7));
    union { uint4 u; bf16x8 v; } f0, f1;
    f0.u.x = u0; f0.u.y = u1; f0.u.z = u2; f0.u.w = u3;
    f1.u.x = u4; f1.u.y = u5; f1.u.z = u6; f1.u.w = u7;

    // PV: acc[vblk] += V-frag(32v x 16k) x P-frag
#pragma unroll
    for (int vblk = 0; vblk < 4; ++vblk) {
      int vrow = vblk * 32 + l31;
      int vswz = ((vrow & 7) ^ ((vrow >> 3) & 3)) << 4;
      const char* vbase = base + 16384 + vrow * 128;
      bf16x8 v0 = *(const bf16x8*)(vbase + ((ks * 64 + h * 16) ^ vswz));
      bf16x8 v1 = *(const bf16x8*)(vbase + ((ks * 64 + 32 + h * 16) ^ vswz));
      acc[vblk] = MFMA32(v0, f0.v, acc[vblk]);
      acc[vblk] = MFMA32(v1, f1.v, acc[vblk]);
    }
  }

  // row-sum: reduce over lane halves (k-coverage split by h)
  prs += __shfl_xor(prs, 32);

  // combine k-halves (ks=1 -> ks=0) through LDS scratch
  float* scr  = (float*)pool;
  float* scrP = (float*)(pool + 32768);
  __syncthreads();
  if (ks == 1) {
#pragma unroll
    for (int vblk = 0; vblk < 4; ++vblk)
#pragma unroll
      for (int rq = 0; rq < 4; ++rq) {
        f32x4 qd;
        qd[0] = acc[vblk][rq * 4 + 0]; qd[1] = acc[vblk][rq * 4 + 1];
        qd[2] = acc[vblk][rq * 4 + 2]; qd[3] = acc[vblk][rq * 4 + 3];
        *(f32x4*)&scr[(((qg * 4 + vblk) * 4 + rq) * 64 + ln) * 4] = qd;
      }
    scrP[qg * 64 + ln] = prs;
  }
  __syncthreads();
  if (ks == 0) {
    float inv = 1.f / (prs + scrP[qg * 64 + ln]);
    int b = bh >> 4, hh = bh & 15;
    size_t orow = ((size_t)(b * LSEQ + q)) * DMODEL + hh * DK;
#pragma unroll
    for (int vblk = 0; vblk < 4; ++vblk) {
      short* obuf = (vblk < 2) ? Om : Os;
      int vbase = (vblk & 1) * 32 + 4 * h;
#pragma unroll
      for (int rq = 0; rq < 4; ++rq) {
        f32x4 od = *(const f32x4*)&scr[(((qg * 4 + vblk) * 4 + rq) * 64 + ln) * 4];
        float o0 = (acc[vblk][rq * 4 + 0] + od[0]) * inv;
        float o1 = (acc[vblk][rq * 4 + 1] + od[1]) * inv;
        float o2 = (acc[vblk][rq * 4 + 2] + od[2]) * inv;
        float o3 = (acc[vblk][rq * 4 + 3] + od[3]) * inv;
        uint2 pk; pk.x = pk2c(o0, o1); pk.y = pk2c(o2, o3);
        *(uint2*)(obuf + orow + vbase + 8 * rq) = pk;
      }
    }
  }
}

extern "C" void kernel_launch(void* const* d_in, const int* in_sizes, int n_in,
                              void* d_out, int out_size, void* d_ws, size_t ws_size,
                              hipStream_t stream) {
  const float* mu    = (const float*)d_in[0];
  const float* sigma = (const float*)d_in[1];
  const float* Wqm   = (const float*)d_in[2];
  const float* bqm   = (const float*)d_in[3];
  const float* Wqs   = (const float*)d_in[4];
  const float* bqs   = (const float*)d_in[5];
  const float* Wo    = (const float*)d_in[6];
  const float* bo    = (const float*)d_in[7];
  float* out = (float*)d_out;
  char* ws = (char*)d_ws;
  const size_t MB = 1u << 20;

  short* Amu   = (short*)(ws + 0);        // 8MB, reused as Om
  short* Asg   = (short*)(ws + 8 * MB);   // 8MB, reused as Os (contiguous with Om)
  short* Wqm_t = (short*)(ws + 16 * MB);  // 6MB
  short* Wqs_t = (short*)(ws + 22 * MB);  // 6MB
  short* Wo_t  = (short*)(ws + 28 * MB);  // 2MB
  short* Qm    = (short*)(ws + 30 * MB);  // 8MB each below
  short* Km    = (short*)(ws + 38 * MB);
  short* VmT   = (short*)(ws + 46 * MB);
  short* Qs    = (short*)(ws + 54 * MB);
  short* Ks    = (short*)(ws + 62 * MB);
  short* VsT   = (short*)(ws + 70 * MB);
  float* sqq   = (float*)(ws + 78 * MB);            // 256KB
  float* sqk   = (float*)(ws + 78 * MB + 256 * 1024);
  short* Om = Amu;
  short* Os = Asg;

  cvt_bf16_k<<<2048, 256, 0, stream>>>(mu, Amu, MTOT * DMODEL / 8);
  cvt_bf16_k<<<2048, 256, 0, stream>>>(sigma, Asg, MTOT * DMODEL / 8);
  cvt_tr_k<<<dim3(96, 32), 256, 0, stream>>>(Wqm, Wqm_t, 1024, 3072);
  cvt_tr_k<<<dim3(96, 32), 256, 0, stream>>>(Wqs, Wqs_t, 1024, 3072);
  cvt_tr_k<<<dim3(32, 32), 256, 0, stream>>>(Wo, Wo_t, 1024, 1024);

  gemm128_k<<<dim3(32, 24), 256, 0, stream>>>(Amu, Wqm_t, bqm, 0, nullptr, Qm, Km, VmT);
  gemm128_k<<<dim3(32, 24), 256, 0, stream>>>(Asg, Wqs_t, bqs, 0, nullptr, Qs, Ks, VsT);

  norms_k<<<512, 256, 0, stream>>>(Qm, Qs, Km, Ks, sqq, sqk);

  attn_k<<<dim3(LSEQ / 64, BH), 256, 0, stream>>>(Qm, Km, VmT, Qs, Ks, VsT, sqq, sqk, Om, Os);

  // out-proj for mu and sigma as ONE GEMM (Om|Os contiguous, M=8192)
  gemm128_k<<<dim3(64, 8), 256, 0, stream>>>(Om, Wo_t, bo, 1, out, nullptr, nullptr, nullptr);
}